// Round 10
// baseline (78.430 us; speedup 1.0000x reference)
//
#include <hip/hip_runtime.h>

// B=32, H=W=512, C=3, toroidal 3x3 uniform depthwise avg + per-pixel quadratic forms.
#define HH 512
#define ROW4 384            // float4 per image row (512*3/4)
#define RPW 4               // rows per wave (best from R6)
#define EPS 0.1f

typedef float vf4 __attribute__((ext_vector_type(4)));   // native vector for nt-store

__device__ __forceinline__ void load_hsum(const float4* __restrict__ rp,
                                          const int* c, float* S, float* rawdst) {
    // g[m] = row[12*t - 4 + m], m = 0..19 (t = lane's first own f4 / 3)
    float4 F0 = rp[c[0]], F1 = rp[c[1]], F2 = rp[c[2]], F3 = rp[c[3]], F4 = rp[c[4]];
    float g[20] = {F0.x,F0.y,F0.z,F0.w, F1.x,F1.y,F1.z,F1.w, F2.x,F2.y,F2.z,F2.w,
                   F3.x,F3.y,F3.z,F3.w, F4.x,F4.y,F4.z,F4.w};
    #pragma unroll
    for (int q = 0; q < 12; ++q) S[q] = g[1+q] + g[4+q] + g[7+q];
    if (rawdst) {
        #pragma unroll
        for (int q = 0; q < 12; ++q) rawdst[q] = g[4+q];   // own 12 floats
    }
}

__global__ __launch_bounds__(256)
void gnllt_kernel(const float* __restrict__ xin,
                  const float* __restrict__ A,
                  const float* __restrict__ Bm,
                  const float* __restrict__ Cm,
                  const float* __restrict__ bias,
                  const float* __restrict__ wk,
                  float* __restrict__ outp)
{
    const int lane  = threadIdx.x & 63;

    // XCD-chunked bijective swizzle: hardware round-robins blockIdx across 8
    // XCDs; remap so work-adjacent blocks (sharing halo rows) sit on the SAME
    // XCD for private-L2 halo reuse. grid=2048, 2048%8==0 -> bijective.
    const int xcd  = blockIdx.x & 7;
    const int slot = blockIdx.x >> 3;
    const int nbid = xcd * ((int)gridDim.x >> 3) + slot;

    const int wid   = (nbid << 2) | (threadIdx.x >> 6);
    const int strip = wid & 1;            // two 256-px strips per row
    const int grp   = wid >> 1;           // 0..4095
    const int img   = grp >> 7;           // 0..31  (128 row-groups per image)
    const int h0    = (grp & 127) * RPW;  // 0..508

    // Uniform parameter loads -> SGPRs. Fold eps*wv^2 into quad coeffs, eps into bias.
    const float wv = wk[0];
    const float qs = EPS * wv * wv;
    const float qa00 = qs*A[0],  qa11 = qs*A[4],  qa22 = qs*A[8];
    const float qa01 = qs*(A[1]+A[3]),  qa02 = qs*(A[2]+A[6]),  qa12 = qs*(A[5]+A[7]);
    const float qb00 = qs*Bm[0], qb11 = qs*Bm[4], qb22 = qs*Bm[8];
    const float qb01 = qs*(Bm[1]+Bm[3]), qb02 = qs*(Bm[2]+Bm[6]), qb12 = qs*(Bm[5]+Bm[7]);
    const float qc00 = qs*Cm[0], qc11 = qs*Cm[4], qc22 = qs*Cm[8];
    const float qc01 = qs*(Cm[1]+Cm[3]), qc02 = qs*(Cm[2]+Cm[6]), qc12 = qs*(Cm[5]+Cm[7]);
    const float bi0 = EPS*bias[0], bi1 = EPS*bias[1], bi2 = EPS*bias[2];

    const float4* x4 = (const float4*)xin;

    // f4-column indices for the 5 overlapping loads (explicit wrap; 384 not pow2)
    const int cb = strip * 192 + 3 * lane;     // first own f4 in row
    int c[5];
    #pragma unroll
    for (int j = 0; j < 5; ++j) {
        int v = cb - 1 + j;
        if (v < 0)     v += ROW4;
        if (v >= ROW4) v -= ROW4;
        c[j] = v;
    }
    const size_t ib = (size_t)img * (HH * ROW4);

    float hs[3][12];    // rolling horizontal-sum rows (compile-time phase indices)
    float raw[12];      // raw row h (for output)
    float rawN[12];     // raw row h+1 in flight

    // Prime: rows h0-1 and h0
    load_hsum(x4 + ib + (size_t)((h0 + HH - 1) & (HH - 1)) * ROW4, c, hs[0], nullptr);
    load_hsum(x4 + ib + (size_t)h0 * ROW4,                         c, hs[1], raw);

    #pragma unroll
    for (int i = 0; i < RPW; ++i) {
        const int r = (h0 + 1 + i) & (HH - 1);
        load_hsum(x4 + ib + (size_t)r * ROW4, c, hs[(2 + i) % 3], rawN);

        const float* hm = hs[i % 3];
        const float* hc = hs[(i + 1) % 3];
        const float* hp = hs[(i + 2) % 3];

        float of[12];
        #pragma unroll
        for (int j = 0; j < 4; ++j) {
            const float s0 = hm[3*j+0] + hc[3*j+0] + hp[3*j+0];
            const float s1 = hm[3*j+1] + hc[3*j+1] + hp[3*j+1];
            const float s2 = hm[3*j+2] + hc[3*j+2] + hp[3*j+2];
            const float p00 = s0*s0, p11 = s1*s1, p22 = s2*s2;
            const float p01 = s0*s1, p02 = s0*s2, p12 = s1*s2;
            of[3*j+0] = raw[3*j+0] + bi0 + qa00*p00 + qa11*p11 + qa22*p22
                                        + qa01*p01 + qa02*p02 + qa12*p12;
            of[3*j+1] = raw[3*j+1] + bi1 + qb00*p00 + qb11*p11 + qb22*p22
                                        + qb01*p01 + qb02*p02 + qb12*p12;
            of[3*j+2] = raw[3*j+2] + bi2 + qc00*p00 + qc11*p11 + qc22*p22
                                        + qc01*p01 + qc02*p02 + qc12*p12;
        }

        // Non-temporal streaming stores (native vec type for the builtin):
        // output is write-once; keep it out of L2/L3 so the input stays
        // cache-resident for the vertical re-reads.
        vf4* op = (vf4*)(outp + 4 * (ib + (size_t)(h0 + i) * ROW4 + cb));
        vf4 v0 = {of[0], of[1], of[2],  of[3]};
        vf4 v1 = {of[4], of[5], of[6],  of[7]};
        vf4 v2 = {of[8], of[9], of[10], of[11]};
        __builtin_nontemporal_store(v0, op + 0);
        __builtin_nontemporal_store(v1, op + 1);
        __builtin_nontemporal_store(v2, op + 2);

        #pragma unroll
        for (int q = 0; q < 12; ++q) raw[q] = rawN[q];
    }
}

extern "C" void kernel_launch(void* const* d_in, const int* in_sizes, int n_in,
                              void* d_out, int out_size, void* d_ws, size_t ws_size,
                              hipStream_t stream) {
    const float* x    = (const float*)d_in[0];
    const float* A    = (const float*)d_in[1];
    const float* Bm   = (const float*)d_in[2];
    const float* Cm   = (const float*)d_in[3];
    const float* bias = (const float*)d_in[4];
    const float* wk   = (const float*)d_in[5];
    float* out = (float*)d_out;

    // 32 imgs x 128 row-groups x 2 strips = 8192 waves = 2048 blocks of 4 waves
    dim3 grid(2048);
    dim3 block(256);
    gnllt_kernel<<<grid, block, 0, stream>>>(x, A, Bm, Cm, bias, wk, out);
}

// Round 11
// 44.428 us; speedup vs baseline: 1.7653x; 1.7653x over previous
//
#include <hip/hip_runtime.h>

// B=32, H=W=512, C=3, toroidal 3x3 uniform depthwise avg + per-pixel quadratic forms.
// Block = 256 threads: stages 6 full input rows into LDS via global_load_lds
// (perfect 16B-stride coalescing), computes 4 output rows.
#define HH 512
#define ROWF 1536           // floats per image row
#define ROW4 384            // float4 per image row
#define EPS 0.1f

typedef const __attribute__((address_space(1))) void* gas_t;
typedef __attribute__((address_space(3))) void* las_t;

__global__ __launch_bounds__(256)
void gnllt_kernel(const float* __restrict__ xin,
                  const float* __restrict__ A,
                  const float* __restrict__ Bm,
                  const float* __restrict__ Cm,
                  const float* __restrict__ bias,
                  const float* __restrict__ wk,
                  float* __restrict__ outp)
{
    __shared__ float lds[6 * ROWF];          // 36,864 B: rows r0-1 .. r0+4 (wrapped)

    const int t    = threadIdx.x;
    const int lane = t & 63;
    const int w    = t >> 6;                 // wave 0..3
    const int blk  = blockIdx.x;             // 0..4095
    const int img  = blk >> 7;               // 0..31
    const int r0   = (blk & 127) << 2;       // first output row: 0..508

    const size_t ib = (size_t)img * (HH * ROW4);   // image base, f4 units

    // ---- Stage 6 rows via global_load_lds: wave w covers flat f4 [576w, 576w+576),
    // 9 instructions x 64 f4. Each 64-f4 chunk lies in one row (64 | 384).
    #pragma unroll
    for (int k = 0; k < 9; ++k) {
        const int u    = 9 * w + k;          // 0..35
        const int row  = u / 6;              // staged row 0..5
        const int col  = (u % 6) * 64;       // f4 col within row
        const int srow = (r0 - 1 + row + HH) & (HH - 1);
        const float* gp = xin + 4 * (ib + (size_t)srow * ROW4 + col + lane);
        float* lp = lds + u * 256;           // u*1024 bytes; HW adds lane*16
        __builtin_amdgcn_global_load_lds((gas_t)gp, (las_t)lp, 16, 0, 0);
    }

    // Uniform parameter loads -> SGPRs (overlap with staging).
    const float wv = wk[0];
    const float qs = EPS * wv * wv;
    const float qa00 = qs*A[0],  qa11 = qs*A[4],  qa22 = qs*A[8];
    const float qa01 = qs*(A[1]+A[3]),  qa02 = qs*(A[2]+A[6]),  qa12 = qs*(A[5]+A[7]);
    const float qb00 = qs*Bm[0], qb11 = qs*Bm[4], qb22 = qs*Bm[8];
    const float qb01 = qs*(Bm[1]+Bm[3]), qb02 = qs*(Bm[2]+Bm[6]), qb12 = qs*(Bm[5]+Bm[7]);
    const float qc00 = qs*Cm[0], qc11 = qs*Cm[4], qc22 = qs*Cm[8];
    const float qc01 = qs*(Cm[1]+Cm[3]), qc02 = qs*(Cm[2]+Cm[6]), qc12 = qs*(Cm[5]+Cm[7]);
    const float bi0 = EPS*bias[0], bi1 = EPS*bias[1], bi2 = EPS*bias[2];

    __syncthreads();   // drains vmcnt(0) before barrier -> staging complete

    // ---- Compute: thread owns 4-px group g of 2 rows (rb, rb+1 of the 4 outputs)
    const int g  = t & 127;                  // px group, p0 = 4g
    const int rb = (t >> 7) << 1;            // 0 or 2

    // f4 window indices within a row (explicit wrap; 384 not pow2)
    int c[5];
    #pragma unroll
    for (int j = 0; j < 5; ++j) {
        int v = 3 * g - 1 + j;
        if (v < 0)     v += ROW4;
        if (v >= ROW4) v -= ROW4;
        c[j] = v;
    }

    float hsv[4][12];    // hsum of staged rows rb+0..rb+3
    float raw[2][12];    // raw centers of output rows rb, rb+1

    #pragma unroll
    for (int s = 0; s < 4; ++s) {
        const float4* lr = (const float4*)(lds + (rb + s) * ROWF);
        const float4 F0 = lr[c[0]], F1 = lr[c[1]], F2 = lr[c[2]],
                     F3 = lr[c[3]], F4 = lr[c[4]];
        const float gg[20] = {F0.x,F0.y,F0.z,F0.w, F1.x,F1.y,F1.z,F1.w,
                              F2.x,F2.y,F2.z,F2.w, F3.x,F3.y,F3.z,F3.w,
                              F4.x,F4.y,F4.z,F4.w};
        #pragma unroll
        for (int q = 0; q < 12; ++q) hsv[s][q] = gg[1+q] + gg[4+q] + gg[7+q];
        if (s == 1 || s == 2) {
            #pragma unroll
            for (int q = 0; q < 12; ++q) raw[s-1][q] = gg[4+q];
        }
    }

    float4* o4 = (float4*)outp;
    #pragma unroll
    for (int k = 0; k < 2; ++k) {
        const float* hm = hsv[k];
        const float* hc = hsv[k + 1];
        const float* hp = hsv[k + 2];
        const float* rw = raw[k];

        float of[12];
        #pragma unroll
        for (int j = 0; j < 4; ++j) {
            const float s0 = hm[3*j+0] + hc[3*j+0] + hp[3*j+0];
            const float s1 = hm[3*j+1] + hc[3*j+1] + hp[3*j+1];
            const float s2 = hm[3*j+2] + hc[3*j+2] + hp[3*j+2];
            const float p00 = s0*s0, p11 = s1*s1, p22 = s2*s2;
            const float p01 = s0*s1, p02 = s0*s2, p12 = s1*s2;
            of[3*j+0] = rw[3*j+0] + bi0 + qa00*p00 + qa11*p11 + qa22*p22
                                        + qa01*p01 + qa02*p02 + qa12*p12;
            of[3*j+1] = rw[3*j+1] + bi1 + qb00*p00 + qb11*p11 + qb22*p22
                                        + qb01*p01 + qb02*p02 + qb12*p12;
            of[3*j+2] = rw[3*j+2] + bi2 + qc00*p00 + qc11*p11 + qc22*p22
                                        + qc01*p01 + qc02*p02 + qc12*p12;
        }

        float4* op = o4 + ib + (size_t)(r0 + rb + k) * ROW4 + 3 * g;
        op[0] = make_float4(of[0], of[1], of[2],  of[3]);
        op[1] = make_float4(of[4], of[5], of[6],  of[7]);
        op[2] = make_float4(of[8], of[9], of[10], of[11]);
    }
}

extern "C" void kernel_launch(void* const* d_in, const int* in_sizes, int n_in,
                              void* d_out, int out_size, void* d_ws, size_t ws_size,
                              hipStream_t stream) {
    const float* x    = (const float*)d_in[0];
    const float* A    = (const float*)d_in[1];
    const float* Bm   = (const float*)d_in[2];
    const float* Cm   = (const float*)d_in[3];
    const float* bias = (const float*)d_in[4];
    const float* wk   = (const float*)d_in[5];
    float* out = (float*)d_out;

    // 32 imgs x 128 four-row groups = 4096 blocks x 256 threads
    dim3 grid(4096);
    dim3 block(256);
    gnllt_kernel<<<grid, block, 0, stream>>>(x, A, Bm, Cm, bias, wk, out);
}

// Round 12
// 42.968 us; speedup vs baseline: 1.8253x; 1.0340x over previous
//
#include <hip/hip_runtime.h>

// B=32, H=W=512, C=3, toroidal 3x3 uniform depthwise avg + per-pixel quadratic forms.
// Software-pipelined: block owns 32 rows (8 groups x 4), double-buffered 6-row LDS
// staging via global_load_lds, counted vmcnt (never drains to 0 mid-loop), raw barriers.
#define HH 512
#define ROWF 1536           // floats per image row
#define ROW4 384            // float4 per image row
#define NG 8                // 4-row groups per block
#define EPS 0.1f

typedef const __attribute__((address_space(1))) void* gas_t;
typedef __attribute__((address_space(3))) void* las_t;

__global__ __launch_bounds__(256)
void gnllt_kernel(const float* __restrict__ xin,
                  const float* __restrict__ A,
                  const float* __restrict__ Bm,
                  const float* __restrict__ Cm,
                  const float* __restrict__ bias,
                  const float* __restrict__ wk,
                  float* __restrict__ outp)
{
    __shared__ float lds[2][6 * ROWF];       // 2 x 36 KB staging buffers

    const int t    = threadIdx.x;
    const int lane = t & 63;
    const int w    = t >> 6;                 // wave 0..3

    // Chunked XCD swizzle (512 % 8 == 0 -> bijective): consecutive work-blocks
    // (sharing halo rows / L2 lines) land on the same XCD.
    const int blk  = (blockIdx.x & 7) * 64 + (blockIdx.x >> 3);
    const int img  = blk >> 4;               // 16 blocks per image
    const int r0   = (blk & 15) << 5;        // 32 rows per block

    const size_t ib = (size_t)img * (HH * ROW4);

    // ---- Uniform params FIRST (keeps vmcnt bookkeeping exact afterwards).
    const float wv = wk[0];
    const float qs = EPS * wv * wv;
    const float qa00 = qs*A[0],  qa11 = qs*A[4],  qa22 = qs*A[8];
    const float qa01 = qs*(A[1]+A[3]),  qa02 = qs*(A[2]+A[6]),  qa12 = qs*(A[5]+A[7]);
    const float qb00 = qs*Bm[0], qb11 = qs*Bm[4], qb22 = qs*Bm[8];
    const float qb01 = qs*(Bm[1]+Bm[3]), qb02 = qs*(Bm[2]+Bm[6]), qb12 = qs*(Bm[5]+Bm[7]);
    const float qc00 = qs*Cm[0], qc11 = qs*Cm[4], qc22 = qs*Cm[8];
    const float qc01 = qs*(Cm[1]+Cm[3]), qc02 = qs*(Cm[2]+Cm[6]), qc12 = qs*(Cm[5]+Cm[7]);
    const float bi0 = EPS*bias[0], bi1 = EPS*bias[1], bi2 = EPS*bias[2];

    // ---- Stage group g (6 rows: r0+4g-1 .. r0+4g+4) into buffer buf.
    // 36 chunks of 64 f4; wave w issues 9 global_load_lds (width 16).
    auto stage = [&](int g, int buf) {
        #pragma unroll
        for (int k = 0; k < 9; ++k) {
            const int u    = 9 * w + k;      // 0..35
            const int row  = u / 6;          // staged row 0..5
            const int col  = (u % 6) * 64;   // f4 col in row
            const int srow = (r0 + 4 * g - 1 + row + HH) & (HH - 1);
            const float* gp = xin + 4 * (ib + (size_t)srow * ROW4 + col + lane);
            float* lp = &lds[buf][0] + u * 256;      // 1024 B per chunk
            __builtin_amdgcn_global_load_lds((gas_t)gp, (las_t)lp, 16, 0, 0);
        }
    };

    stage(0, 0);
    stage(1, 1);

    // ---- Compute decomposition: thread owns 4-px group g4 on 2 of the 4 rows.
    const int g4 = t & 127;                  // pixel group, first px = 4*g4
    const int rb = (t >> 7) << 1;            // 0 or 2

    int c[5];                                // f4 window indices (explicit wrap)
    #pragma unroll
    for (int j = 0; j < 5; ++j) {
        int v = 3 * g4 - 1 + j;
        if (v < 0)     v += ROW4;
        if (v >= ROW4) v -= ROW4;
        c[j] = v;
    }

    float4* o4 = (float4*)outp;

    #pragma unroll
    for (int i = 0; i < NG; ++i) {
        // Counted waits: group i's 9 loads done; keep newer (stores + next stage)
        // in flight. In-order vmcnt retirement (m135) makes these exact.
        if (i == 0)           asm volatile("s_waitcnt vmcnt(9)"  ::: "memory");
        else if (i < NG - 1)  asm volatile("s_waitcnt vmcnt(15)" ::: "memory");
        else                  asm volatile("s_waitcnt vmcnt(6)"  ::: "memory");
        __builtin_amdgcn_s_barrier();        // raw: no vmcnt(0) drain

        const float* B = &lds[i & 1][0];

        float hsv[4][12];    // hsum of staged rows rb..rb+3
        float raw[2][12];
        #pragma unroll
        for (int s = 0; s < 4; ++s) {
            const float4* lr = (const float4*)(B + (rb + s) * ROWF);
            const float4 F0 = lr[c[0]], F1 = lr[c[1]], F2 = lr[c[2]],
                         F3 = lr[c[3]], F4 = lr[c[4]];
            const float gg[20] = {F0.x,F0.y,F0.z,F0.w, F1.x,F1.y,F1.z,F1.w,
                                  F2.x,F2.y,F2.z,F2.w, F3.x,F3.y,F3.z,F3.w,
                                  F4.x,F4.y,F4.z,F4.w};
            #pragma unroll
            for (int q = 0; q < 12; ++q) hsv[s][q] = gg[1+q] + gg[4+q] + gg[7+q];
            if (s == 1 || s == 2) {
                #pragma unroll
                for (int q = 0; q < 12; ++q) raw[s-1][q] = gg[4+q];
            }
        }
        asm volatile("s_waitcnt lgkmcnt(0)" ::: "memory");
        __builtin_amdgcn_s_barrier();        // all waves done reading this buffer

        #pragma unroll
        for (int k = 0; k < 2; ++k) {
            const float* hm = hsv[k];
            const float* hc = hsv[k + 1];
            const float* hp = hsv[k + 2];
            const float* rw = raw[k];

            float of[12];
            #pragma unroll
            for (int j = 0; j < 4; ++j) {
                const float s0 = hm[3*j+0] + hc[3*j+0] + hp[3*j+0];
                const float s1 = hm[3*j+1] + hc[3*j+1] + hp[3*j+1];
                const float s2 = hm[3*j+2] + hc[3*j+2] + hp[3*j+2];
                const float p00 = s0*s0, p11 = s1*s1, p22 = s2*s2;
                const float p01 = s0*s1, p02 = s0*s2, p12 = s1*s2;
                of[3*j+0] = rw[3*j+0] + bi0 + qa00*p00 + qa11*p11 + qa22*p22
                                            + qa01*p01 + qa02*p02 + qa12*p12;
                of[3*j+1] = rw[3*j+1] + bi1 + qb00*p00 + qb11*p11 + qb22*p22
                                            + qb01*p01 + qb02*p02 + qb12*p12;
                of[3*j+2] = rw[3*j+2] + bi2 + qc00*p00 + qc11*p11 + qc22*p22
                                            + qc01*p01 + qc02*p02 + qc12*p12;
            }

            float4* op = o4 + ib + (size_t)(r0 + 4*i + rb + k) * ROW4 + 3 * g4;
            op[0] = make_float4(of[0], of[1], of[2],  of[3]);
            op[1] = make_float4(of[4], of[5], of[6],  of[7]);
            op[2] = make_float4(of[8], of[9], of[10], of[11]);
        }

        // Prefetch group i+2 into the buffer we just finished reading.
        if (i + 2 < NG) stage(i + 2, i & 1);
    }
}

extern "C" void kernel_launch(void* const* d_in, const int* in_sizes, int n_in,
                              void* d_out, int out_size, void* d_ws, size_t ws_size,
                              hipStream_t stream) {
    const float* x    = (const float*)d_in[0];
    const float* A    = (const float*)d_in[1];
    const float* Bm   = (const float*)d_in[2];
    const float* Cm   = (const float*)d_in[3];
    const float* bias = (const float*)d_in[4];
    const float* wk   = (const float*)d_in[5];
    float* out = (float*)d_out;

    // 32 imgs x 16 blocks (32 rows each) = 512 blocks; 2/CU (72KB LDS) = full residency
    dim3 grid(512);
    dim3 block(256);
    gnllt_kernel<<<grid, block, 0, stream>>>(x, A, Bm, Cm, bias, wk, out);
}

// Round 13
// 41.506 us; speedup vs baseline: 1.8896x; 1.0352x over previous
//
#include <hip/hip_runtime.h>

// B=32, H=W=512, C=3, toroidal 3x3 uniform depthwise avg + per-pixel quadratic forms.
// R6 structure (best: 42.65us) + ONE change: dense stores via wave-private LDS
// transpose (48B-stride lane writes -> 16B-stride lane reads -> 1KB-dense global
// stores). Isolates write-request amplification.
#define HH 512
#define ROW4 384            // float4 per image row (512*3/4)
#define RPW 4               // rows per wave (best from R6)
#define EPS 0.1f

__device__ __forceinline__ void load_hsum(const float4* __restrict__ rp,
                                          const int* c, float* S, float* rawdst) {
    float4 F0 = rp[c[0]], F1 = rp[c[1]], F2 = rp[c[2]], F3 = rp[c[3]], F4 = rp[c[4]];
    float g[20] = {F0.x,F0.y,F0.z,F0.w, F1.x,F1.y,F1.z,F1.w, F2.x,F2.y,F2.z,F2.w,
                   F3.x,F3.y,F3.z,F3.w, F4.x,F4.y,F4.z,F4.w};
    #pragma unroll
    for (int q = 0; q < 12; ++q) S[q] = g[1+q] + g[4+q] + g[7+q];
    if (rawdst) {
        #pragma unroll
        for (int q = 0; q < 12; ++q) rawdst[q] = g[4+q];   // own 12 floats
    }
}

__global__ __launch_bounds__(256)
void gnllt_kernel(const float* __restrict__ xin,
                  const float* __restrict__ A,
                  const float* __restrict__ Bm,
                  const float* __restrict__ Cm,
                  const float* __restrict__ bias,
                  const float* __restrict__ wk,
                  float* __restrict__ outp)
{
    __shared__ float4 obuf[4][192];          // 12 KB: wave-private transpose slices

    const int lane  = threadIdx.x & 63;
    const int wsub  = threadIdx.x >> 6;
    const int wid   = (blockIdx.x << 2) | wsub;
    const int strip = wid & 1;            // two 256-px strips per row
    const int grp   = wid >> 1;           // 0..4095
    const int img   = grp >> 7;           // 0..31  (128 row-groups per image)
    const int h0    = (grp & 127) * RPW;  // 0..508

    // Uniform parameter loads -> SGPRs. Fold eps*wv^2 into quad coeffs, eps into bias.
    const float wv = wk[0];
    const float qs = EPS * wv * wv;
    const float qa00 = qs*A[0],  qa11 = qs*A[4],  qa22 = qs*A[8];
    const float qa01 = qs*(A[1]+A[3]),  qa02 = qs*(A[2]+A[6]),  qa12 = qs*(A[5]+A[7]);
    const float qb00 = qs*Bm[0], qb11 = qs*Bm[4], qb22 = qs*Bm[8];
    const float qb01 = qs*(Bm[1]+Bm[3]), qb02 = qs*(Bm[2]+Bm[6]), qb12 = qs*(Bm[5]+Bm[7]);
    const float qc00 = qs*Cm[0], qc11 = qs*Cm[4], qc22 = qs*Cm[8];
    const float qc01 = qs*(Cm[1]+Cm[3]), qc02 = qs*(Cm[2]+Cm[6]), qc12 = qs*(Cm[5]+Cm[7]);
    const float bi0 = EPS*bias[0], bi1 = EPS*bias[1], bi2 = EPS*bias[2];

    const float4* x4 = (const float4*)xin;
    float4*       o4 = (float4*)outp;
    float4*       ob = obuf[wsub];

    // f4-column indices for the 5 overlapping loads (explicit wrap; 384 not pow2)
    const int cb = strip * 192 + 3 * lane;     // first own f4 in row
    int c[5];
    #pragma unroll
    for (int j = 0; j < 5; ++j) {
        int v = cb - 1 + j;
        if (v < 0)     v += ROW4;
        if (v >= ROW4) v -= ROW4;
        c[j] = v;
    }
    const size_t ib = (size_t)img * (HH * ROW4);

    float hs[3][12];    // rolling horizontal-sum rows (compile-time phase indices)
    float raw[12];      // raw row h (for output)
    float rawN[12];     // raw row h+1 in flight

    // Prime: rows h0-1 and h0
    load_hsum(x4 + ib + (size_t)((h0 + HH - 1) & (HH - 1)) * ROW4, c, hs[0], nullptr);
    load_hsum(x4 + ib + (size_t)h0 * ROW4,                         c, hs[1], raw);

    #pragma unroll
    for (int i = 0; i < RPW; ++i) {
        const int r = (h0 + 1 + i) & (HH - 1);
        load_hsum(x4 + ib + (size_t)r * ROW4, c, hs[(2 + i) % 3], rawN);

        const float* hm = hs[i % 3];
        const float* hc = hs[(i + 1) % 3];
        const float* hp = hs[(i + 2) % 3];

        float of[12];
        #pragma unroll
        for (int j = 0; j < 4; ++j) {
            const float s0 = hm[3*j+0] + hc[3*j+0] + hp[3*j+0];
            const float s1 = hm[3*j+1] + hc[3*j+1] + hp[3*j+1];
            const float s2 = hm[3*j+2] + hc[3*j+2] + hp[3*j+2];
            const float p00 = s0*s0, p11 = s1*s1, p22 = s2*s2;
            const float p01 = s0*s1, p02 = s0*s2, p12 = s1*s2;
            of[3*j+0] = raw[3*j+0] + bi0 + qa00*p00 + qa11*p11 + qa22*p22
                                        + qa01*p01 + qa02*p02 + qa12*p12;
            of[3*j+1] = raw[3*j+1] + bi1 + qb00*p00 + qb11*p11 + qb22*p22
                                        + qb01*p01 + qb02*p02 + qb12*p12;
            of[3*j+2] = raw[3*j+2] + bi2 + qc00*p00 + qc11*p11 + qc22*p22
                                        + qc01*p01 + qc02*p02 + qc12*p12;
        }

        // Wave-private LDS transpose: 48B-stride writes (12l mod 32 -> all banks
        // covered once per 8 lanes, conflict-free), in-wave fence, 16B-stride
        // reads -> 3 fully-dense 1KB global store instructions.
        ob[3*lane + 0] = make_float4(of[0], of[1], of[2],  of[3]);
        ob[3*lane + 1] = make_float4(of[4], of[5], of[6],  of[7]);
        ob[3*lane + 2] = make_float4(of[8], of[9], of[10], of[11]);
        asm volatile("s_waitcnt lgkmcnt(0)" ::: "memory");
        const float4 s0 = ob[lane], s1 = ob[lane + 64], s2 = ob[lane + 128];

        float4* op = o4 + ib + (size_t)(h0 + i) * ROW4 + strip * 192;
        op[lane]       = s0;
        op[lane + 64]  = s1;
        op[lane + 128] = s2;

        #pragma unroll
        for (int q = 0; q < 12; ++q) raw[q] = rawN[q];
    }
}

extern "C" void kernel_launch(void* const* d_in, const int* in_sizes, int n_in,
                              void* d_out, int out_size, void* d_ws, size_t ws_size,
                              hipStream_t stream) {
    const float* x    = (const float*)d_in[0];
    const float* A    = (const float*)d_in[1];
    const float* Bm   = (const float*)d_in[2];
    const float* Cm   = (const float*)d_in[3];
    const float* bias = (const float*)d_in[4];
    const float* wk   = (const float*)d_in[5];
    float* out = (float*)d_out;

    // 32 imgs x 128 row-groups x 2 strips = 8192 waves = 2048 blocks of 4 waves
    dim3 grid(2048);
    dim3 block(256);
    gnllt_kernel<<<grid, block, 0, stream>>>(x, A, Bm, Cm, bias, wk, out);
}

// Round 14
// 39.635 us; speedup vs baseline: 1.9788x; 1.0472x over previous
//
#include <hip/hip_runtime.h>

// B=32, H=W=512, C=3, toroidal 3x3 uniform depthwise avg + per-pixel quadratic forms.
// R13 structure (41.5us: reg-separable conv + wave-private LDS store transpose)
// + ONE change: dense stores are NON-TEMPORAL. Dense full-line nt writes bypass
// L2/L3 without partial-line amplification (R10's failure mode), so the 100MB
// input stays L3-resident across replays -> FETCH_SIZE collapses.
#define HH 512
#define ROW4 384            // float4 per image row (512*3/4)
#define RPW 4               // rows per wave (best from R6)
#define EPS 0.1f

typedef float vf4 __attribute__((ext_vector_type(4)));   // native vec for nt-store

__device__ __forceinline__ void load_hsum(const float4* __restrict__ rp,
                                          const int* c, float* S, float* rawdst) {
    float4 F0 = rp[c[0]], F1 = rp[c[1]], F2 = rp[c[2]], F3 = rp[c[3]], F4 = rp[c[4]];
    float g[20] = {F0.x,F0.y,F0.z,F0.w, F1.x,F1.y,F1.z,F1.w, F2.x,F2.y,F2.z,F2.w,
                   F3.x,F3.y,F3.z,F3.w, F4.x,F4.y,F4.z,F4.w};
    #pragma unroll
    for (int q = 0; q < 12; ++q) S[q] = g[1+q] + g[4+q] + g[7+q];
    if (rawdst) {
        #pragma unroll
        for (int q = 0; q < 12; ++q) rawdst[q] = g[4+q];   // own 12 floats
    }
}

__global__ __launch_bounds__(256)
void gnllt_kernel(const float* __restrict__ xin,
                  const float* __restrict__ A,
                  const float* __restrict__ Bm,
                  const float* __restrict__ Cm,
                  const float* __restrict__ bias,
                  const float* __restrict__ wk,
                  float* __restrict__ outp)
{
    __shared__ float4 obuf[4][192];          // 12 KB: wave-private transpose slices

    const int lane  = threadIdx.x & 63;
    const int wsub  = threadIdx.x >> 6;
    const int wid   = (blockIdx.x << 2) | wsub;
    const int strip = wid & 1;            // two 256-px strips per row
    const int grp   = wid >> 1;           // 0..4095
    const int img   = grp >> 7;           // 0..31  (128 row-groups per image)
    const int h0    = (grp & 127) * RPW;  // 0..508

    // Uniform parameter loads -> SGPRs. Fold eps*wv^2 into quad coeffs, eps into bias.
    const float wv = wk[0];
    const float qs = EPS * wv * wv;
    const float qa00 = qs*A[0],  qa11 = qs*A[4],  qa22 = qs*A[8];
    const float qa01 = qs*(A[1]+A[3]),  qa02 = qs*(A[2]+A[6]),  qa12 = qs*(A[5]+A[7]);
    const float qb00 = qs*Bm[0], qb11 = qs*Bm[4], qb22 = qs*Bm[8];
    const float qb01 = qs*(Bm[1]+Bm[3]), qb02 = qs*(Bm[2]+Bm[6]), qb12 = qs*(Bm[5]+Bm[7]);
    const float qc00 = qs*Cm[0], qc11 = qs*Cm[4], qc22 = qs*Cm[8];
    const float qc01 = qs*(Cm[1]+Cm[3]), qc02 = qs*(Cm[2]+Cm[6]), qc12 = qs*(Cm[5]+Cm[7]);
    const float bi0 = EPS*bias[0], bi1 = EPS*bias[1], bi2 = EPS*bias[2];

    const float4* x4 = (const float4*)xin;
    float4*       ob = obuf[wsub];

    // f4-column indices for the 5 overlapping loads (explicit wrap; 384 not pow2)
    const int cb = strip * 192 + 3 * lane;     // first own f4 in row
    int c[5];
    #pragma unroll
    for (int j = 0; j < 5; ++j) {
        int v = cb - 1 + j;
        if (v < 0)     v += ROW4;
        if (v >= ROW4) v -= ROW4;
        c[j] = v;
    }
    const size_t ib = (size_t)img * (HH * ROW4);

    float hs[3][12];    // rolling horizontal-sum rows (compile-time phase indices)
    float raw[12];      // raw row h (for output)
    float rawN[12];     // raw row h+1 in flight

    // Prime: rows h0-1 and h0
    load_hsum(x4 + ib + (size_t)((h0 + HH - 1) & (HH - 1)) * ROW4, c, hs[0], nullptr);
    load_hsum(x4 + ib + (size_t)h0 * ROW4,                         c, hs[1], raw);

    #pragma unroll
    for (int i = 0; i < RPW; ++i) {
        const int r = (h0 + 1 + i) & (HH - 1);
        load_hsum(x4 + ib + (size_t)r * ROW4, c, hs[(2 + i) % 3], rawN);

        const float* hm = hs[i % 3];
        const float* hc = hs[(i + 1) % 3];
        const float* hp = hs[(i + 2) % 3];

        float of[12];
        #pragma unroll
        for (int j = 0; j < 4; ++j) {
            const float s0 = hm[3*j+0] + hc[3*j+0] + hp[3*j+0];
            const float s1 = hm[3*j+1] + hc[3*j+1] + hp[3*j+1];
            const float s2 = hm[3*j+2] + hc[3*j+2] + hp[3*j+2];
            const float p00 = s0*s0, p11 = s1*s1, p22 = s2*s2;
            const float p01 = s0*s1, p02 = s0*s2, p12 = s1*s2;
            of[3*j+0] = raw[3*j+0] + bi0 + qa00*p00 + qa11*p11 + qa22*p22
                                        + qa01*p01 + qa02*p02 + qa12*p12;
            of[3*j+1] = raw[3*j+1] + bi1 + qb00*p00 + qb11*p11 + qb22*p22
                                        + qb01*p01 + qb02*p02 + qb12*p12;
            of[3*j+2] = raw[3*j+2] + bi2 + qc00*p00 + qc11*p11 + qc22*p22
                                        + qc01*p01 + qc02*p02 + qc12*p12;
        }

        // Wave-private LDS transpose (proven conflict-free in R13), in-wave
        // fence, then 3 fully-dense 1KB NON-TEMPORAL store instructions:
        // full 128B-line coverage per instr -> merges to full-line HBM bursts
        // while bypassing L2/L3 (input stays cache-resident).
        ob[3*lane + 0] = make_float4(of[0], of[1], of[2],  of[3]);
        ob[3*lane + 1] = make_float4(of[4], of[5], of[6],  of[7]);
        ob[3*lane + 2] = make_float4(of[8], of[9], of[10], of[11]);
        asm volatile("s_waitcnt lgkmcnt(0)" ::: "memory");
        const float4 s0 = ob[lane], s1 = ob[lane + 64], s2 = ob[lane + 128];

        vf4* op = (vf4*)(outp + 4 * (ib + (size_t)(h0 + i) * ROW4 + strip * 192));
        vf4 v0 = {s0.x, s0.y, s0.z, s0.w};
        vf4 v1 = {s1.x, s1.y, s1.z, s1.w};
        vf4 v2 = {s2.x, s2.y, s2.z, s2.w};
        __builtin_nontemporal_store(v0, op + lane);
        __builtin_nontemporal_store(v1, op + lane + 64);
        __builtin_nontemporal_store(v2, op + lane + 128);

        #pragma unroll
        for (int q = 0; q < 12; ++q) raw[q] = rawN[q];
    }
}

extern "C" void kernel_launch(void* const* d_in, const int* in_sizes, int n_in,
                              void* d_out, int out_size, void* d_ws, size_t ws_size,
                              hipStream_t stream) {
    const float* x    = (const float*)d_in[0];
    const float* A    = (const float*)d_in[1];
    const float* Bm   = (const float*)d_in[2];
    const float* Cm   = (const float*)d_in[3];
    const float* bias = (const float*)d_in[4];
    const float* wk   = (const float*)d_in[5];
    float* out = (float*)d_out;

    // 32 imgs x 128 row-groups x 2 strips = 8192 waves = 2048 blocks of 4 waves
    dim3 grid(2048);
    dim3 block(256);
    gnllt_kernel<<<grid, block, 0, stream>>>(x, A, Bm, Cm, bias, wk, out);
}

// Round 15
// 39.042 us; speedup vs baseline: 2.0088x; 1.0152x over previous
//
#include <hip/hip_runtime.h>

// B=32, H=W=512, C=3, toroidal 3x3 uniform depthwise avg + per-pixel quadratic forms.
// R14 (39.6us: reg-separable conv + LDS store-transpose + dense nt stores)
// + ONE change: 2-deep row prefetch (load row i+2 at iter i; consume row i+1
// loaded a full iteration earlier) -> per-wave latency slack.
#define HH 512
#define ROW4 384            // float4 per image row (512*3/4)
#define RPW 4
#define EPS 0.1f

typedef float vf4 __attribute__((ext_vector_type(4)));

__device__ __forceinline__ void loadF(const float4* __restrict__ rp,
                                      const int* c, float4* F) {
    F[0] = rp[c[0]]; F[1] = rp[c[1]]; F[2] = rp[c[2]];
    F[3] = rp[c[3]]; F[4] = rp[c[4]];
}

__device__ __forceinline__ void hsumF(const float4* F, float* S, float* rawdst) {
    const float g[20] = {F[0].x,F[0].y,F[0].z,F[0].w, F[1].x,F[1].y,F[1].z,F[1].w,
                         F[2].x,F[2].y,F[2].z,F[2].w, F[3].x,F[3].y,F[3].z,F[3].w,
                         F[4].x,F[4].y,F[4].z,F[4].w};
    #pragma unroll
    for (int q = 0; q < 12; ++q) S[q] = g[1+q] + g[4+q] + g[7+q];
    if (rawdst) {
        #pragma unroll
        for (int q = 0; q < 12; ++q) rawdst[q] = g[4+q];
    }
}

__global__ __launch_bounds__(256)
void gnllt_kernel(const float* __restrict__ xin,
                  const float* __restrict__ A,
                  const float* __restrict__ Bm,
                  const float* __restrict__ Cm,
                  const float* __restrict__ bias,
                  const float* __restrict__ wk,
                  float* __restrict__ outp)
{
    __shared__ float4 obuf[4][192];          // 12 KB: wave-private transpose slices

    const int lane  = threadIdx.x & 63;
    const int wsub  = threadIdx.x >> 6;
    const int wid   = (blockIdx.x << 2) | wsub;
    const int strip = wid & 1;
    const int grp   = wid >> 1;              // 0..4095
    const int img   = grp >> 7;              // 0..31
    const int h0    = (grp & 127) * RPW;     // 0..508

    const float wv = wk[0];
    const float qs = EPS * wv * wv;
    const float qa00 = qs*A[0],  qa11 = qs*A[4],  qa22 = qs*A[8];
    const float qa01 = qs*(A[1]+A[3]),  qa02 = qs*(A[2]+A[6]),  qa12 = qs*(A[5]+A[7]);
    const float qb00 = qs*Bm[0], qb11 = qs*Bm[4], qb22 = qs*Bm[8];
    const float qb01 = qs*(Bm[1]+Bm[3]), qb02 = qs*(Bm[2]+Bm[6]), qb12 = qs*(Bm[5]+Bm[7]);
    const float qc00 = qs*Cm[0], qc11 = qs*Cm[4], qc22 = qs*Cm[8];
    const float qc01 = qs*(Cm[1]+Cm[3]), qc02 = qs*(Cm[2]+Cm[6]), qc12 = qs*(Cm[5]+Cm[7]);
    const float bi0 = EPS*bias[0], bi1 = EPS*bias[1], bi2 = EPS*bias[2];

    const float4* x4 = (const float4*)xin;
    float4*       ob = obuf[wsub];

    const int cb = strip * 192 + 3 * lane;
    int c[5];
    #pragma unroll
    for (int j = 0; j < 5; ++j) {
        int v = cb - 1 + j;
        if (v < 0)     v += ROW4;
        if (v >= ROW4) v -= ROW4;
        c[j] = v;
    }
    const size_t ib = (size_t)img * (HH * ROW4);

    // row pointer helper (wrap)
    auto rowp = [&](int r) {
        return x4 + ib + (size_t)((h0 + r + HH) & (HH - 1)) * ROW4;
    };

    float hs[3][12];     // hsum slot(r) = (r+1)%3
    float raw[2][12];    // raw(r) in raw[r&1]
    float4 Fb[2][5];     // F(r) in Fb[r&1] (double-buffered prefetch)
    float4 T0[5], T1[5];

    // Prime: issue loads for rows -1, 0, +1 back-to-back, then hsums.
    loadF(rowp(-1), c, T0);
    loadF(rowp(0),  c, T1);
    loadF(rowp(1),  c, Fb[1]);
    hsumF(T0, hs[0], nullptr);      // row -1 -> slot 0
    hsumF(T1, hs[1], raw[0]);       // row  0 -> slot 1, raw(0)

    #pragma unroll
    for (int i = 0; i < RPW; ++i) {
        // 1) Prefetch row i+2 (2-deep): issued before any dependent use.
        if (i < RPW - 1) loadF(rowp(i + 2), c, Fb[i & 1]);

        // 2) Consume F(i+1), loaded a full iteration ago.
        hsumF(Fb[(i + 1) & 1], hs[(i + 2) % 3], raw[(i + 1) & 1]);

        const float* hm = hs[i % 3];
        const float* hc = hs[(i + 1) % 3];
        const float* hp = hs[(i + 2) % 3];
        const float* rw = raw[i & 1];

        float of[12];
        #pragma unroll
        for (int j = 0; j < 4; ++j) {
            const float s0 = hm[3*j+0] + hc[3*j+0] + hp[3*j+0];
            const float s1 = hm[3*j+1] + hc[3*j+1] + hp[3*j+1];
            const float s2 = hm[3*j+2] + hc[3*j+2] + hp[3*j+2];
            const float p00 = s0*s0, p11 = s1*s1, p22 = s2*s2;
            const float p01 = s0*s1, p02 = s0*s2, p12 = s1*s2;
            of[3*j+0] = rw[3*j+0] + bi0 + qa00*p00 + qa11*p11 + qa22*p22
                                        + qa01*p01 + qa02*p02 + qa12*p12;
            of[3*j+1] = rw[3*j+1] + bi1 + qb00*p00 + qb11*p11 + qb22*p22
                                        + qb01*p01 + qb02*p02 + qb12*p12;
            of[3*j+2] = rw[3*j+2] + bi2 + qc00*p00 + qc11*p11 + qc22*p22
                                        + qc01*p01 + qc02*p02 + qc12*p12;
        }

        // Wave-private LDS transpose (conflict-free), in-wave fence, then
        // 3 dense 1KB non-temporal store instructions.
        ob[3*lane + 0] = make_float4(of[0], of[1], of[2],  of[3]);
        ob[3*lane + 1] = make_float4(of[4], of[5], of[6],  of[7]);
        ob[3*lane + 2] = make_float4(of[8], of[9], of[10], of[11]);
        asm volatile("s_waitcnt lgkmcnt(0)" ::: "memory");
        const float4 s0 = ob[lane], s1 = ob[lane + 64], s2 = ob[lane + 128];

        vf4* op = (vf4*)(outp + 4 * (ib + (size_t)(h0 + i) * ROW4 + strip * 192));
        vf4 v0 = {s0.x, s0.y, s0.z, s0.w};
        vf4 v1 = {s1.x, s1.y, s1.z, s1.w};
        vf4 v2 = {s2.x, s2.y, s2.z, s2.w};
        __builtin_nontemporal_store(v0, op + lane);
        __builtin_nontemporal_store(v1, op + lane + 64);
        __builtin_nontemporal_store(v2, op + lane + 128);
    }
}

extern "C" void kernel_launch(void* const* d_in, const int* in_sizes, int n_in,
                              void* d_out, int out_size, void* d_ws, size_t ws_size,
                              hipStream_t stream) {
    const float* x    = (const float*)d_in[0];
    const float* A    = (const float*)d_in[1];
    const float* Bm   = (const float*)d_in[2];
    const float* Cm   = (const float*)d_in[3];
    const float* bias = (const float*)d_in[4];
    const float* wk   = (const float*)d_in[5];
    float* out = (float*)d_out;

    dim3 grid(2048);
    dim3 block(256);
    gnllt_kernel<<<grid, block, 0, stream>>>(x, A, Bm, Cm, bias, wk, out);
}

// Round 16
// 36.125 us; speedup vs baseline: 2.1711x; 1.0808x over previous
//
#include <hip/hip_runtime.h>

// B=32, H=W=512, C=3, toroidal 3x3 uniform depthwise avg + per-pixel quadratic forms.
// R15 (39.0us: reg-separable conv + 2-deep prefetch + LDS store-transpose + dense
// nt stores) + ONE change: RPW 4 -> 16 (cuts L2 read amplification 1.5x -> 1.125x;
// rolling window keeps VGPR footprint constant).
#define HH 512
#define ROW4 384            // float4 per image row (512*3/4)
#define RPW 16
#define EPS 0.1f

typedef float vf4 __attribute__((ext_vector_type(4)));

__device__ __forceinline__ void loadF(const float4* __restrict__ rp,
                                      const int* c, float4* F) {
    F[0] = rp[c[0]]; F[1] = rp[c[1]]; F[2] = rp[c[2]];
    F[3] = rp[c[3]]; F[4] = rp[c[4]];
}

__device__ __forceinline__ void hsumF(const float4* F, float* S, float* rawdst) {
    const float g[20] = {F[0].x,F[0].y,F[0].z,F[0].w, F[1].x,F[1].y,F[1].z,F[1].w,
                         F[2].x,F[2].y,F[2].z,F[2].w, F[3].x,F[3].y,F[3].z,F[3].w,
                         F[4].x,F[4].y,F[4].z,F[4].w};
    #pragma unroll
    for (int q = 0; q < 12; ++q) S[q] = g[1+q] + g[4+q] + g[7+q];
    if (rawdst) {
        #pragma unroll
        for (int q = 0; q < 12; ++q) rawdst[q] = g[4+q];
    }
}

__global__ __launch_bounds__(256)
void gnllt_kernel(const float* __restrict__ xin,
                  const float* __restrict__ A,
                  const float* __restrict__ Bm,
                  const float* __restrict__ Cm,
                  const float* __restrict__ bias,
                  const float* __restrict__ wk,
                  float* __restrict__ outp)
{
    __shared__ float4 obuf[4][192];          // 12 KB: wave-private transpose slices

    const int lane  = threadIdx.x & 63;
    const int wsub  = threadIdx.x >> 6;
    const int wid   = (blockIdx.x << 2) | wsub;
    const int strip = wid & 1;
    const int grp   = wid >> 1;              // 0..1023
    const int img   = grp >> 5;              // 0..31  (32 row-groups per image)
    const int h0    = (grp & 31) * RPW;      // 0..496

    const float wv = wk[0];
    const float qs = EPS * wv * wv;
    const float qa00 = qs*A[0],  qa11 = qs*A[4],  qa22 = qs*A[8];
    const float qa01 = qs*(A[1]+A[3]),  qa02 = qs*(A[2]+A[6]),  qa12 = qs*(A[5]+A[7]);
    const float qb00 = qs*Bm[0], qb11 = qs*Bm[4], qb22 = qs*Bm[8];
    const float qb01 = qs*(Bm[1]+Bm[3]), qb02 = qs*(Bm[2]+Bm[6]), qb12 = qs*(Bm[5]+Bm[7]);
    const float qc00 = qs*Cm[0], qc11 = qs*Cm[4], qc22 = qs*Cm[8];
    const float qc01 = qs*(Cm[1]+Cm[3]), qc02 = qs*(Cm[2]+Cm[6]), qc12 = qs*(Cm[5]+Cm[7]);
    const float bi0 = EPS*bias[0], bi1 = EPS*bias[1], bi2 = EPS*bias[2];

    const float4* x4 = (const float4*)xin;
    float4*       ob = obuf[wsub];

    const int cb = strip * 192 + 3 * lane;
    int c[5];
    #pragma unroll
    for (int j = 0; j < 5; ++j) {
        int v = cb - 1 + j;
        if (v < 0)     v += ROW4;
        if (v >= ROW4) v -= ROW4;
        c[j] = v;
    }
    const size_t ib = (size_t)img * (HH * ROW4);

    auto rowp = [&](int r) {
        return x4 + ib + (size_t)((h0 + r + HH) & (HH - 1)) * ROW4;
    };

    float hs[3][12];     // hsum slot(r) = (r+1)%3
    float raw[2][12];    // raw(r) in raw[r&1]
    float4 Fb[2][5];     // F(r) in Fb[r&1] (double-buffered prefetch)
    float4 T0[5], T1[5];

    // Prime: rows -1, 0 (immediate), row +1 prefetched.
    loadF(rowp(-1), c, T0);
    loadF(rowp(0),  c, T1);
    loadF(rowp(1),  c, Fb[1]);
    hsumF(T0, hs[0], nullptr);
    hsumF(T1, hs[1], raw[0]);

    #pragma unroll
    for (int i = 0; i < RPW; ++i) {
        // 1) Prefetch row i+2 (2-deep).
        if (i < RPW - 1) loadF(rowp(i + 2), c, Fb[i & 1]);

        // 2) Consume F(i+1), loaded a full iteration ago.
        hsumF(Fb[(i + 1) & 1], hs[(i + 2) % 3], raw[(i + 1) & 1]);

        const float* hm = hs[i % 3];
        const float* hc = hs[(i + 1) % 3];
        const float* hp = hs[(i + 2) % 3];
        const float* rw = raw[i & 1];

        float of[12];
        #pragma unroll
        for (int j = 0; j < 4; ++j) {
            const float s0 = hm[3*j+0] + hc[3*j+0] + hp[3*j+0];
            const float s1 = hm[3*j+1] + hc[3*j+1] + hp[3*j+1];
            const float s2 = hm[3*j+2] + hc[3*j+2] + hp[3*j+2];
            const float p00 = s0*s0, p11 = s1*s1, p22 = s2*s2;
            const float p01 = s0*s1, p02 = s0*s2, p12 = s1*s2;
            of[3*j+0] = rw[3*j+0] + bi0 + qa00*p00 + qa11*p11 + qa22*p22
                                        + qa01*p01 + qa02*p02 + qa12*p12;
            of[3*j+1] = rw[3*j+1] + bi1 + qb00*p00 + qb11*p11 + qb22*p22
                                        + qb01*p01 + qb02*p02 + qb12*p12;
            of[3*j+2] = rw[3*j+2] + bi2 + qc00*p00 + qc11*p11 + qc22*p22
                                        + qc01*p01 + qc02*p02 + qc12*p12;
        }

        // Wave-private LDS transpose (conflict-free), in-wave fence, then
        // 3 dense 1KB non-temporal store instructions.
        ob[3*lane + 0] = make_float4(of[0], of[1], of[2],  of[3]);
        ob[3*lane + 1] = make_float4(of[4], of[5], of[6],  of[7]);
        ob[3*lane + 2] = make_float4(of[8], of[9], of[10], of[11]);
        asm volatile("s_waitcnt lgkmcnt(0)" ::: "memory");
        const float4 s0 = ob[lane], s1 = ob[lane + 64], s2 = ob[lane + 128];

        vf4* op = (vf4*)(outp + 4 * (ib + (size_t)(h0 + i) * ROW4 + strip * 192));
        vf4 v0 = {s0.x, s0.y, s0.z, s0.w};
        vf4 v1 = {s1.x, s1.y, s1.z, s1.w};
        vf4 v2 = {s2.x, s2.y, s2.z, s2.w};
        __builtin_nontemporal_store(v0, op + lane);
        __builtin_nontemporal_store(v1, op + lane + 64);
        __builtin_nontemporal_store(v2, op + lane + 128);
    }
}

extern "C" void kernel_launch(void* const* d_in, const int* in_sizes, int n_in,
                              void* d_out, int out_size, void* d_ws, size_t ws_size,
                              hipStream_t stream) {
    const float* x    = (const float*)d_in[0];
    const float* A    = (const float*)d_in[1];
    const float* Bm   = (const float*)d_in[2];
    const float* Cm   = (const float*)d_in[3];
    const float* bias = (const float*)d_in[4];
    const float* wk   = (const float*)d_in[5];
    float* out = (float*)d_out;

    // 32 imgs x 32 row-groups x 2 strips = 2048 waves = 512 blocks of 4 waves
    dim3 grid(512);
    dim3 block(256);
    gnllt_kernel<<<grid, block, 0, stream>>>(x, A, Bm, Cm, bias, wk, out);
}

// Round 17
// 35.423 us; speedup vs baseline: 2.2141x; 1.0198x over previous
//
#include <hip/hip_runtime.h>

// B=32, H=W=512, C=3, toroidal 3x3 uniform depthwise avg + per-pixel quadratic forms.
// R16 (36.1us) + ONE change: RPW 16 -> 32 (read amp 1.125x -> 1.0625x).
// Grid = 256 blocks = exactly 1 per CU, zero tail.
#define HH 512
#define ROW4 384            // float4 per image row (512*3/4)
#define RPW 32
#define EPS 0.1f

typedef float vf4 __attribute__((ext_vector_type(4)));

__device__ __forceinline__ void loadF(const float4* __restrict__ rp,
                                      const int* c, float4* F) {
    F[0] = rp[c[0]]; F[1] = rp[c[1]]; F[2] = rp[c[2]];
    F[3] = rp[c[3]]; F[4] = rp[c[4]];
}

__device__ __forceinline__ void hsumF(const float4* F, float* S, float* rawdst) {
    const float g[20] = {F[0].x,F[0].y,F[0].z,F[0].w, F[1].x,F[1].y,F[1].z,F[1].w,
                         F[2].x,F[2].y,F[2].z,F[2].w, F[3].x,F[3].y,F[3].z,F[3].w,
                         F[4].x,F[4].y,F[4].z,F[4].w};
    #pragma unroll
    for (int q = 0; q < 12; ++q) S[q] = g[1+q] + g[4+q] + g[7+q];
    if (rawdst) {
        #pragma unroll
        for (int q = 0; q < 12; ++q) rawdst[q] = g[4+q];
    }
}

__global__ __launch_bounds__(256)
void gnllt_kernel(const float* __restrict__ xin,
                  const float* __restrict__ A,
                  const float* __restrict__ Bm,
                  const float* __restrict__ Cm,
                  const float* __restrict__ bias,
                  const float* __restrict__ wk,
                  float* __restrict__ outp)
{
    __shared__ float4 obuf[4][192];          // 12 KB: wave-private transpose slices

    const int lane  = threadIdx.x & 63;
    const int wsub  = threadIdx.x >> 6;
    const int wid   = (blockIdx.x << 2) | wsub;
    const int strip = wid & 1;
    const int grp   = wid >> 1;              // 0..511
    const int img   = grp >> 4;              // 0..31  (16 row-groups per image)
    const int h0    = (grp & 15) * RPW;      // 0..480

    const float wv = wk[0];
    const float qs = EPS * wv * wv;
    const float qa00 = qs*A[0],  qa11 = qs*A[4],  qa22 = qs*A[8];
    const float qa01 = qs*(A[1]+A[3]),  qa02 = qs*(A[2]+A[6]),  qa12 = qs*(A[5]+A[7]);
    const float qb00 = qs*Bm[0], qb11 = qs*Bm[4], qb22 = qs*Bm[8];
    const float qb01 = qs*(Bm[1]+Bm[3]), qb02 = qs*(Bm[2]+Bm[6]), qb12 = qs*(Bm[5]+Bm[7]);
    const float qc00 = qs*Cm[0], qc11 = qs*Cm[4], qc22 = qs*Cm[8];
    const float qc01 = qs*(Cm[1]+Cm[3]), qc02 = qs*(Cm[2]+Cm[6]), qc12 = qs*(Cm[5]+Cm[7]);
    const float bi0 = EPS*bias[0], bi1 = EPS*bias[1], bi2 = EPS*bias[2];

    const float4* x4 = (const float4*)xin;
    float4*       ob = obuf[wsub];

    const int cb = strip * 192 + 3 * lane;
    int c[5];
    #pragma unroll
    for (int j = 0; j < 5; ++j) {
        int v = cb - 1 + j;
        if (v < 0)     v += ROW4;
        if (v >= ROW4) v -= ROW4;
        c[j] = v;
    }
    const size_t ib = (size_t)img * (HH * ROW4);

    auto rowp = [&](int r) {
        return x4 + ib + (size_t)((h0 + r + HH) & (HH - 1)) * ROW4;
    };

    float hs[3][12];     // hsum slot(r) = (r+1)%3
    float raw[2][12];    // raw(r) in raw[r&1]
    float4 Fb[2][5];     // F(r) in Fb[r&1] (double-buffered prefetch)
    float4 T0[5], T1[5];

    // Prime: rows -1, 0 (immediate), row +1 prefetched.
    loadF(rowp(-1), c, T0);
    loadF(rowp(0),  c, T1);
    loadF(rowp(1),  c, Fb[1]);
    hsumF(T0, hs[0], nullptr);
    hsumF(T1, hs[1], raw[0]);

    #pragma unroll
    for (int i = 0; i < RPW; ++i) {
        // 1) Prefetch row i+2 (2-deep).
        if (i < RPW - 1) loadF(rowp(i + 2), c, Fb[i & 1]);

        // 2) Consume F(i+1), loaded a full iteration ago.
        hsumF(Fb[(i + 1) & 1], hs[(i + 2) % 3], raw[(i + 1) & 1]);

        const float* hm = hs[i % 3];
        const float* hc = hs[(i + 1) % 3];
        const float* hp = hs[(i + 2) % 3];
        const float* rw = raw[i & 1];

        float of[12];
        #pragma unroll
        for (int j = 0; j < 4; ++j) {
            const float s0 = hm[3*j+0] + hc[3*j+0] + hp[3*j+0];
            const float s1 = hm[3*j+1] + hc[3*j+1] + hp[3*j+1];
            const float s2 = hm[3*j+2] + hc[3*j+2] + hp[3*j+2];
            const float p00 = s0*s0, p11 = s1*s1, p22 = s2*s2;
            const float p01 = s0*s1, p02 = s0*s2, p12 = s1*s2;
            of[3*j+0] = rw[3*j+0] + bi0 + qa00*p00 + qa11*p11 + qa22*p22
                                        + qa01*p01 + qa02*p02 + qa12*p12;
            of[3*j+1] = rw[3*j+1] + bi1 + qb00*p00 + qb11*p11 + qb22*p22
                                        + qb01*p01 + qb02*p02 + qb12*p12;
            of[3*j+2] = rw[3*j+2] + bi2 + qc00*p00 + qc11*p11 + qc22*p22
                                        + qc01*p01 + qc02*p02 + qc12*p12;
        }

        // Wave-private LDS transpose (conflict-free), in-wave fence, then
        // 3 dense 1KB non-temporal store instructions.
        ob[3*lane + 0] = make_float4(of[0], of[1], of[2],  of[3]);
        ob[3*lane + 1] = make_float4(of[4], of[5], of[6],  of[7]);
        ob[3*lane + 2] = make_float4(of[8], of[9], of[10], of[11]);
        asm volatile("s_waitcnt lgkmcnt(0)" ::: "memory");
        const float4 s0 = ob[lane], s1 = ob[lane + 64], s2 = ob[lane + 128];

        vf4* op = (vf4*)(outp + 4 * (ib + (size_t)(h0 + i) * ROW4 + strip * 192));
        vf4 v0 = {s0.x, s0.y, s0.z, s0.w};
        vf4 v1 = {s1.x, s1.y, s1.z, s1.w};
        vf4 v2 = {s2.x, s2.y, s2.z, s2.w};
        __builtin_nontemporal_store(v0, op + lane);
        __builtin_nontemporal_store(v1, op + lane + 64);
        __builtin_nontemporal_store(v2, op + lane + 128);
    }
}

extern "C" void kernel_launch(void* const* d_in, const int* in_sizes, int n_in,
                              void* d_out, int out_size, void* d_ws, size_t ws_size,
                              hipStream_t stream) {
    const float* x    = (const float*)d_in[0];
    const float* A    = (const float*)d_in[1];
    const float* Bm   = (const float*)d_in[2];
    const float* Cm   = (const float*)d_in[3];
    const float* bias = (const float*)d_in[4];
    const float* wk   = (const float*)d_in[5];
    float* out = (float*)d_out;

    // 32 imgs x 16 row-groups x 2 strips = 1024 waves = 256 blocks (1 per CU)
    dim3 grid(256);
    dim3 block(256);
    gnllt_kernel<<<grid, block, 0, stream>>>(x, A, Bm, Cm, bias, wk, out);
}